// Round 1
// baseline (353.881 us; speedup 1.0000x reference)
//
#include <hip/hip_runtime.h>
#include <hip/hip_bf16.h>

#define GAMMA 0.002f
#define NROWS 8192
#define MROWS 8192
#define DDIM  512

typedef __attribute__((ext_vector_type(8))) short bf16x8;
typedef __attribute__((ext_vector_type(4))) float f32x4;
typedef __attribute__((ext_vector_type(8))) unsigned short ushort8;

static __device__ __forceinline__ unsigned short f32_to_bf16_rne(float f) {
    unsigned int u = __float_as_uint(f);
    unsigned int lsb = (u >> 16) & 1u;
    u += 0x7fffu + lsb;
    return (unsigned short)(u >> 16);
}

// One wave (64 threads) per row: cast fp32 row -> bf16, compute fp32 row norm.
__global__ __launch_bounds__(64) void prep_kernel(const float* __restrict__ src,
                                                  unsigned short* __restrict__ dstb,
                                                  float* __restrict__ sq) {
    const int row  = blockIdx.x;
    const int lane = threadIdx.x;

    const float4* p = (const float4*)(src + (size_t)row * DDIM) + lane * 2;
    float4 f0 = p[0];
    float4 f1 = p[1];

    float s = f0.x*f0.x + f0.y*f0.y + f0.z*f0.z + f0.w*f0.w
            + f1.x*f1.x + f1.y*f1.y + f1.z*f1.z + f1.w*f1.w;

    float t[8] = {f0.x, f0.y, f0.z, f0.w, f1.x, f1.y, f1.z, f1.w};
    ushort8 hv;
#pragma unroll
    for (int i = 0; i < 8; ++i) hv[i] = f32_to_bf16_rne(t[i]);
    *(ushort8*)(dstb + (size_t)row * DDIM + lane * 8) = hv;

#pragma unroll
    for (int off = 32; off > 0; off >>= 1) s += __shfl_down(s, off);
    if (lane == 0) sq[row] = s;
}

// 128x128 output tile per block, 256 threads (4 waves, 2x2), BK=32.
// A = x (bf16, row-major N x D), B = y (bf16, row-major M x D), C = A * B^T
// fused with the RBF epilogue.
__global__ __launch_bounds__(256) void rbf_gemm_kernel(
        const unsigned short* __restrict__ xb,
        const unsigned short* __restrict__ yb,
        const float* __restrict__ xsq,
        const float* __restrict__ ysq,
        float* __restrict__ out) {
    // A tile: 128 rows x 32 k bf16 = 8 KiB, contiguous [row][k] (64 B/row).
    // B tile: same. No padding (global_load_lds needs contiguity).
    __shared__ __align__(16) unsigned short smem[2 * 128 * 32];
    unsigned short* smemA = smem;
    unsigned short* smemB = smem + 128 * 32;

    const int tid  = threadIdx.x;
    const int wave = tid >> 6;
    const int lane = tid & 63;

    const int rowBase = blockIdx.x * 128;
    const int colBase = blockIdx.y * 128;

    const int wm = wave >> 1;  // 0..1 (row half)
    const int wn = wave & 1;   // 0..1 (col half)

    f32x4 acc[4][4];
#pragma unroll
    for (int i = 0; i < 4; ++i)
#pragma unroll
        for (int j = 0; j < 4; ++j) acc[i][j] = (f32x4){0.f, 0.f, 0.f, 0.f};

    // Staging lane mapping: LDS dst = seg_base + lane*16; that byte lands at
    // row (lane/4) within the 16-row segment, k-byte (lane%4)*16 of the 64 B row.
    const int srow = lane >> 2;
    const int skb  = (lane & 3) * 16;

    // Fragment read mapping (A and B identical for the B^T layout):
    // frag row = lane&15 (within 16-row tile), k bytes = (lane>>4)*16.
    const int fr  = lane & 15;
    const int fkb = (lane >> 4) * 16;

    for (int kt = 0; kt < DDIM / 32; ++kt) {
        const int k0b = kt * 64;  // byte offset of this k-tile within a row
#pragma unroll
        for (int r = 0; r < 2; ++r) {
            const int seg = r * 4 + wave;  // 0..7 (16 rows each)
            {
                const char* g = (const char*)xb
                    + ((size_t)(rowBase + seg * 16 + srow) * DDIM) * 2 + k0b + skb;
                __builtin_amdgcn_global_load_lds(
                    (__attribute__((address_space(1))) void*)g,
                    (__attribute__((address_space(3))) void*)((char*)smemA + seg * 1024),
                    16, 0, 0);
            }
            {
                const char* g = (const char*)yb
                    + ((size_t)(colBase + seg * 16 + srow) * DDIM) * 2 + k0b + skb;
                __builtin_amdgcn_global_load_lds(
                    (__attribute__((address_space(1))) void*)g,
                    (__attribute__((address_space(3))) void*)((char*)smemB + seg * 1024),
                    16, 0, 0);
            }
        }
        __syncthreads();  // drains vmcnt (global_load_lds) before compute

        bf16x8 a[4], b[4];
#pragma unroll
        for (int i = 0; i < 4; ++i)
            a[i] = *(const bf16x8*)((const char*)smemA + (wm * 64 + i * 16 + fr) * 64 + fkb);
#pragma unroll
        for (int j = 0; j < 4; ++j)
            b[j] = *(const bf16x8*)((const char*)smemB + (wn * 64 + j * 16 + fr) * 64 + fkb);

#pragma unroll
        for (int i = 0; i < 4; ++i)
#pragma unroll
            for (int j = 0; j < 4; ++j)
                acc[i][j] = __builtin_amdgcn_mfma_f32_16x16x32_bf16(a[i], b[j], acc[i][j], 0, 0, 0);

        __syncthreads();  // protect LDS before next stage
    }

    // Epilogue: C/D layout col = lane&15, row = (lane>>4)*4 + reg  [m89/m91]
    const int q4 = (lane >> 4) * 4;
#pragma unroll
    for (int i = 0; i < 4; ++i) {
        float xr[4];
#pragma unroll
        for (int r2 = 0; r2 < 4; ++r2)
            xr[r2] = xsq[rowBase + wm * 64 + i * 16 + q4 + r2];
#pragma unroll
        for (int j = 0; j < 4; ++j) {
            const int gcol = colBase + wn * 64 + j * 16 + fr;
            const float yc = ysq[gcol];
#pragma unroll
            for (int r2 = 0; r2 < 4; ++r2) {
                const int grow = rowBase + wm * 64 + i * 16 + q4 + r2;
                float d = xr[r2] + yc - 2.0f * acc[i][j][r2];
                d = fmaxf(d, 0.0f);
                out[(size_t)grow * MROWS + gcol] = __expf(-GAMMA * d);
            }
        }
    }
}

extern "C" void kernel_launch(void* const* d_in, const int* in_sizes, int n_in,
                              void* d_out, int out_size, void* d_ws, size_t ws_size,
                              hipStream_t stream) {
    const float* x = (const float*)d_in[0];
    const float* y = (const float*)d_in[1];
    float* out = (float*)d_out;

    // Workspace layout: xb (8 MiB) | yb (8 MiB) | xsq (32 KiB) | ysq (32 KiB)
    unsigned short* xb = (unsigned short*)d_ws;
    unsigned short* yb = xb + (size_t)NROWS * DDIM;
    float* xsq = (float*)(yb + (size_t)MROWS * DDIM);
    float* ysq = xsq + NROWS;

    prep_kernel<<<NROWS, 64, 0, stream>>>(x, xb, xsq);
    prep_kernel<<<MROWS, 64, 0, stream>>>(y, yb, ysq);

    dim3 grid(NROWS / 128, MROWS / 128);
    rbf_gemm_kernel<<<grid, 256, 0, stream>>>(xb, yb, xsq, ysq, out);
}